// Round 3
// baseline (142.303 us; speedup 1.0000x reference)
//
#include <hip/hip_runtime.h>

typedef __attribute__((ext_vector_type(8))) short short8;
typedef __attribute__((ext_vector_type(4))) float f32x4;

#define C_DIM 128
#define K_CODES 1024
#define TOT 8388608   // 16*128*64*64
#define NBLK 512      // 128 contiguous pixels per block

__device__ __forceinline__ unsigned int f2bf1(float f) {
  unsigned int u = __float_as_uint(f);
  return (u + 0x7FFFu + ((u >> 16) & 1u)) >> 16;   // RNE fp32->bf16
}
__device__ __forceinline__ unsigned int f2bf2(float lo, float hi) {
  return f2bf1(lo) | (f2bf1(hi) << 16);
}

union U16x8 { uint4 u; short8 s; };

// ---- P: bf16 codebook + (1 + ||e||^2) + zero flags/accumulators ----
// R8 post-mortem: R7's grid=256 with float4/uint2 granularity was 2x the
// element count -> wrote 512KB into the 256KB ebf, clobbering nsq1/used/
// done. Correct thread count for 16B-read/8B-write granules: K*C/4 = 32768
// -> grid 128. R9: fix fence spelling (__builtin_amdgcn_fence; the
// __hip_atomic_fence identifier doesn't exist in this ROCm).
__global__ void prep_kernel(const float* __restrict__ cb,
                            unsigned short* __restrict__ ebf,
                            float* __restrict__ nsq1,
                            int* __restrict__ used,
                            unsigned int* __restrict__ done,
                            int* __restrict__ usedCnt,
                            float* __restrict__ lossAcc) {
  int gid = blockIdx.x * 256 + threadIdx.x;     // 128 blocks * 256 = 32768 = K*C/4
  const float4 v = ((const float4*)cb)[gid];    // 32768*16B = 512KB = cb size
  uint2 pk;
  pk.x = f2bf2(v.x, v.y);
  pk.y = f2bf2(v.z, v.w);
  ((uint2*)ebf)[gid] = pk;                      // 32768*8B = 256KB = ebf size
  if (gid < K_CODES) {
    float s = 0.f;
    #pragma unroll 8
    for (int c = 0; c < C_DIM; ++c) { float w = cb[gid * C_DIM + c]; s += w * w; }
    nsq1[gid] = 1.0f + s;      // +1 keeps d positive -> u32-monotone float bits
    used[gid] = 0;
  }
  if (gid == 0) { *done = 0; *usedCnt = 0; *lossAcc = 0.f; }
}

// ---- M: block = 128 px; wave = 64 px x 512 codes (half-split); B via LDS ----
// R6: LDS-shared B staging cut vq_main 79 -> ~38us. vq_main sits at the
// 268MB bidirectional HBM roofline (fills calibrate 6.46 TB/s -> 41.5us).
// R8: finalize fused via IC-performed RMWs only (no fence-dependent array
// re-read): used-dedup atomicOr + usedCnt atomicAdd (both returning ->
// vmcnt retire == performed at coherence point), loss into one atomic f32,
// RELEASE done-counter (drains prior RMW), last block acquire-fences and
// reads 2 scalars. No XCD-L2 staleness exposure by construction.
// Math (verified R4-R6): A=bf16(-2z), MFMA C-init = 1+||e||^2 -> d directly;
// key=(bits(d)&~1023)|code, argmin via u32 min.
// launch_bounds(256,3): ~170 reg cap, live set ~140 (NO spill — R2 lesson).
__global__ __launch_bounds__(256, 3)
void vq_main(const float* __restrict__ zin,
             const unsigned short* __restrict__ ebf,
             const float* __restrict__ nsq1,
             int* __restrict__ used,
             unsigned int* __restrict__ done,
             int* __restrict__ usedCnt,
             float* __restrict__ lossAcc,
             float* __restrict__ out) {
  __shared__ __align__(16) uint4 bG[2][1024];   // 2 x 16KB: 64-code chunks
  __shared__ float nsq_s[K_CODES];
  __shared__ unsigned int mergeK[128][2];
  __shared__ int   widx[128];
  __shared__ float wsum[4];
  __shared__ int   amLast;

  const int t  = threadIdx.x;
  const int L  = t & 63;
  const int wv = t >> 6;        // wave 0..3
  const int ph = wv >> 1;       // pixel half: px [ph*64, ph*64+64)
  const int kh = wv & 1;        // code half: jj tiles {kh*2, kh*2+1}
  const int q  = L >> 4;        // lane quad
  const int nL = L & 15;

  const int bb = blockIdx.x >> 5;          // batch 0..15
  const int hg = blockIdx.x & 31;          // 128-px group
  const int zoff = bb * (C_DIM * 4096) + hg * 128;   // + c*4096 + p

  for (int i = t; i < K_CODES; i += 256) nsq_s[i] = nsq1[i];

  // ---- A fragments straight from global, packed bf16(-2z) in-register
  // lane L, m-tile mt (0..3): pixel = ph*64 + mt*16 + nL, k = ks*32 + q*8 + u
  short8 afrag[16];
  #pragma unroll
  for (int mt = 0; mt < 4; ++mt) {
    const int wcol = ph * 64 + mt * 16 + nL;
    #pragma unroll
    for (int ks = 0; ks < 4; ++ks) {
      float v[8];
      #pragma unroll
      for (int u = 0; u < 8; ++u)
        v[u] = zin[zoff + (ks * 32 + q * 8 + u) * 4096 + wcol];
      U16x8 pk;
      pk.u.x = f2bf2(-2.f * v[0], -2.f * v[1]);
      pk.u.y = f2bf2(-2.f * v[2], -2.f * v[3]);
      pk.u.z = f2bf2(-2.f * v[4], -2.f * v[5]);
      pk.u.w = f2bf2(-2.f * v[6], -2.f * v[7]);
      afrag[mt * 4 + ks] = pk.s;
    }
  }

  // ---- staging thread roles (contiguous 1KB per wave-instruction)
  const uint4* __restrict__ ebv = (const uint4*)ebf;   // granule view, row=16
  const int nLw = t >> 4;        // row-within-group 0..15
  const int oct = t & 15;        // granule-within-row
  const int sks = oct >> 2, sq = oct & 3;

  // stage chunk 0
  #pragma unroll
  for (int p = 0; p < 4; ++p) {
    int r = p * 16 + nLw;                        // row within chunk
    bG[0][p * 256 + sks * 64 + nLw * 4 + sq] = ebv[r * 16 + oct];
  }
  __syncthreads();

  unsigned int kmin[16];
  #pragma unroll
  for (int i = 0; i < 16; ++i) kmin[i] = 0xFFFFFFFFu;

  // ---- K loop: 16 chunks; this wave consumes its 2 jj-tiles (32 codes)
  #pragma unroll 1
  for (int ch = 0; ch < 16; ++ch) {
    const int cur = ch & 1;
    if (ch < 15) {                               // stage next chunk into !cur
      #pragma unroll
      for (int p = 0; p < 4; ++p) {
        int r = p * 16 + nLw;
        bG[cur ^ 1][p * 256 + sks * 64 + nLw * 4 + sq] =
            ebv[((ch + 1) * 64 + r) * 16 + oct];
      }
    }
    const short8* bp = (const short8*)bG[cur];
    #pragma unroll
    for (int j2 = 0; j2 < 2; ++j2) {
      const int jj = kh * 2 + j2;
      const int row = ch * 64 + jj * 16 + nL;    // this lane's code
      short8 b0 = bp[jj * 256 + 0 * 64 + nL * 4 + q];
      short8 b1 = bp[jj * 256 + 1 * 64 + nL * 4 + q];
      short8 b2 = bp[jj * 256 + 2 * 64 + nL * 4 + q];
      short8 b3 = bp[jj * 256 + 3 * 64 + nL * 4 + q];
      const float nv = nsq_s[row];
      f32x4 a0 = {nv, nv, nv, nv};
      f32x4 a1 = {nv, nv, nv, nv};
      f32x4 a2 = {nv, nv, nv, nv};
      f32x4 a3 = {nv, nv, nv, nv};
      a0 = __builtin_amdgcn_mfma_f32_16x16x32_bf16(afrag[0],  b0, a0, 0, 0, 0);
      a1 = __builtin_amdgcn_mfma_f32_16x16x32_bf16(afrag[4],  b0, a1, 0, 0, 0);
      a2 = __builtin_amdgcn_mfma_f32_16x16x32_bf16(afrag[8],  b0, a2, 0, 0, 0);
      a3 = __builtin_amdgcn_mfma_f32_16x16x32_bf16(afrag[12], b0, a3, 0, 0, 0);
      a0 = __builtin_amdgcn_mfma_f32_16x16x32_bf16(afrag[1],  b1, a0, 0, 0, 0);
      a1 = __builtin_amdgcn_mfma_f32_16x16x32_bf16(afrag[5],  b1, a1, 0, 0, 0);
      a2 = __builtin_amdgcn_mfma_f32_16x16x32_bf16(afrag[9],  b1, a2, 0, 0, 0);
      a3 = __builtin_amdgcn_mfma_f32_16x16x32_bf16(afrag[13], b1, a3, 0, 0, 0);
      a0 = __builtin_amdgcn_mfma_f32_16x16x32_bf16(afrag[2],  b2, a0, 0, 0, 0);
      a1 = __builtin_amdgcn_mfma_f32_16x16x32_bf16(afrag[6],  b2, a1, 0, 0, 0);
      a2 = __builtin_amdgcn_mfma_f32_16x16x32_bf16(afrag[10], b2, a2, 0, 0, 0);
      a3 = __builtin_amdgcn_mfma_f32_16x16x32_bf16(afrag[14], b2, a3, 0, 0, 0);
      a0 = __builtin_amdgcn_mfma_f32_16x16x32_bf16(afrag[3],  b3, a0, 0, 0, 0);
      a1 = __builtin_amdgcn_mfma_f32_16x16x32_bf16(afrag[7],  b3, a1, 0, 0, 0);
      a2 = __builtin_amdgcn_mfma_f32_16x16x32_bf16(afrag[11], b3, a2, 0, 0, 0);
      a3 = __builtin_amdgcn_mfma_f32_16x16x32_bf16(afrag[15], b3, a3, 0, 0, 0);
      const unsigned int rowc = (unsigned int)row;
      #pragma unroll
      for (int r = 0; r < 4; ++r) {
        unsigned int k0 = (__float_as_uint(a0[r]) & 0xFFFFFC00u) | rowc;
        if (k0 < kmin[r]) kmin[r] = k0;
        unsigned int k1 = (__float_as_uint(a1[r]) & 0xFFFFFC00u) | rowc;
        if (k1 < kmin[4 + r]) kmin[4 + r] = k1;
        unsigned int k2 = (__float_as_uint(a2[r]) & 0xFFFFFC00u) | rowc;
        if (k2 < kmin[8 + r]) kmin[8 + r] = k2;
        unsigned int k3 = (__float_as_uint(a3[r]) & 0xFFFFFC00u) | rowc;
        if (k3 < kmin[12 + r]) kmin[12 + r] = k3;
      }
    }
    __syncthreads();   // next-chunk writes visible; cur free for re-stage
  }

  // ---- in-wave butterfly u32-min over the 16 code-lanes of each quad
  #pragma unroll
  for (int m = 1; m <= 8; m <<= 1) {
    #pragma unroll
    for (int i = 0; i < 16; ++i) {
      unsigned int o = (unsigned int)__shfl_xor((int)kmin[i], m, 64);
      if (o < kmin[i]) kmin[i] = o;
    }
  }
  if (nL == 0) {
    #pragma unroll
    for (int mt = 0; mt < 4; ++mt)
      #pragma unroll
      for (int r = 0; r < 4; ++r)
        mergeK[ph * 64 + mt * 16 + q * 4 + r][kh] = kmin[mt * 4 + r];
  }
  __syncthreads();

  // ---- cross-half merge (2-way u32 min per pixel) + IC-performed used-dedup
  if (t < 128) {
    unsigned int b = min(mergeK[t][0], mergeK[t][1]);
    int bi = (int)(b & 1023u);
    widx[t] = bi;
    // returning RMW -> executed at coherence point; vmcnt retire == performed.
    int old = atomicOr(&used[bi], 1);
    if (old == 0) {
      int d = atomicAdd(usedCnt, 1);           // returning form (sink keeps it)
      asm volatile("" :: "v"(d));
    }
    // latency hidden under the gather loop below
  }
  __syncthreads();

  // ---- gather bf16 e-row + coalesced z/out + loss partial
  float lsum = 0.f;
  {
    const int p = t & 127, cg = t >> 7;    // 2 channel halves x 64 ch
    const int idx = widx[p];
    const uint4* erow = ebv + idx * 16 + cg * 8;
    const int obase = zoff + cg * 64 * 4096 + p;
    #pragma unroll 2
    for (int i = 0; i < 8; ++i) {
      uint4 g = erow[i];
      const unsigned int wrd[4] = {g.x, g.y, g.z, g.w};
      #pragma unroll
      for (int half = 0; half < 4; ++half) {
        float e0 = __uint_as_float(wrd[half] << 16);
        float e1 = __uint_as_float(wrd[half] & 0xFFFF0000u);
        int off = obase + (i * 8 + half * 2) * 4096;
        float d0 = zin[off] - e0;
        out[off] = e0;                     // lanes over p -> 256B contiguous
        lsum += d0 * d0;
        off += 4096;
        float d1 = zin[off] - e1;
        out[off] = e1;
        lsum += d1 * d1;
      }
    }
  }
  #pragma unroll
  for (int o = 32; o > 0; o >>= 1) lsum += __shfl_down(lsum, o, 64);
  if (L == 0) wsum[wv] = lsum;
  __syncthreads();
  // each thread's RMWs retired (== performed at IC) at the barrier drain

  // ---- fused finalize: all cross-block state is IC-resident RMW results
  if (t == 0) {
    float bs = wsum[0] + wsum[1] + wsum[2] + wsum[3];
    float oldl = __hip_atomic_fetch_add(lossAcc, bs, __ATOMIC_RELAXED,
                                        __HIP_MEMORY_SCOPE_AGENT);
    asm volatile("" :: "v"(oldl));   // returning form: performed before counter
    // RELEASE: drains prior vmem (incl. the loss RMW) before the counter op
    unsigned int oldc = __hip_atomic_fetch_add(done, 1u, __ATOMIC_RELEASE,
                                               __HIP_MEMORY_SCOPE_AGENT);
    amLast = (oldc == (unsigned int)(NBLK - 1)) ? 1 : 0;
  }
  __syncthreads();
  if (amLast && t == 0) {
    __builtin_amdgcn_fence(__ATOMIC_ACQUIRE, "agent");
    float ltot = __hip_atomic_load(lossAcc, __ATOMIC_RELAXED,
                                   __HIP_MEMORY_SCOPE_AGENT);
    int   uc   = __hip_atomic_load(usedCnt, __ATOMIC_RELAXED,
                                   __HIP_MEMORY_SCOPE_AGENT);
    out[TOT]     = 1.25f * ltot / (float)TOT;  // (1+0.25)*MSE
    out[TOT + 1] = (float)uc / 1024.0f;
  }
}

extern "C" void kernel_launch(void* const* d_in, const int* in_sizes, int n_in,
                              void* d_out, int out_size, void* d_ws, size_t ws_size,
                              hipStream_t stream) {
  const float* z  = (const float*)d_in[0];
  const float* cb = (const float*)d_in[1];
  float* out = (float*)d_out;
  char* ws = (char*)d_ws;
  unsigned short* ebf = (unsigned short*)ws;          // 262144 B
  float* nsq1  = (float*)(ws + 262144);               // 4096 B
  int*   used  = (int*)(ws + 266240);                 // 4096 B
  unsigned int* done = (unsigned int*)(ws + 270336);  // 4 B
  int*   usedCnt = (int*)(ws + 270352);               // 4 B
  float* lossAcc = (float*)(ws + 270368);             // 4 B

  hipLaunchKernelGGL(prep_kernel, dim3(128), dim3(256), 0, stream,
                     cb, ebf, nsq1, used, done, usedCnt, lossAcc);
  hipLaunchKernelGGL(vq_main, dim3(NBLK), dim3(256), 0, stream,
                     z, ebf, nsq1, used, done, usedCnt, lossAcc, out);
}

// Round 4
// 130.955 us; speedup vs baseline: 1.0867x; 1.0867x over previous
//
#include <hip/hip_runtime.h>

typedef __attribute__((ext_vector_type(8))) short short8;
typedef __attribute__((ext_vector_type(4))) float f32x4;

#define C_DIM 128
#define K_CODES 1024
#define TOT 8388608   // 16*128*64*64
#define NBLK 512      // 128 contiguous pixels per block

__device__ __forceinline__ unsigned int f2bf1(float f) {
  unsigned int u = __float_as_uint(f);
  return (u + 0x7FFFu + ((u >> 16) & 1u)) >> 16;   // RNE fp32->bf16
}
__device__ __forceinline__ unsigned int f2bf2(float lo, float hi) {
  return f2bf1(lo) | (f2bf1(hi) << 16);
}

union U16x8 { uint4 u; short8 s; };

// ---- P: bf16 codebook + (1 + ||e||^2) + zero flags/accumulators ----
// Grid 128: 32768 threads x (16B read / 8B write) == K*C exactly (R8 lesson).
__global__ void prep_kernel(const float* __restrict__ cb,
                            unsigned short* __restrict__ ebf,
                            float* __restrict__ nsq1,
                            int* __restrict__ used,
                            unsigned int* __restrict__ done,
                            int* __restrict__ usedCnt,
                            float* __restrict__ lossAcc) {
  int gid = blockIdx.x * 256 + threadIdx.x;     // 128 blocks * 256 = 32768 = K*C/4
  const float4 v = ((const float4*)cb)[gid];    // 32768*16B = 512KB = cb size
  uint2 pk;
  pk.x = f2bf2(v.x, v.y);
  pk.y = f2bf2(v.z, v.w);
  ((uint2*)ebf)[gid] = pk;                      // 32768*8B = 256KB = ebf size
  if (gid < K_CODES) {
    float s = 0.f;
    #pragma unroll 8
    for (int c = 0; c < C_DIM; ++c) { float w = cb[gid * C_DIM + c]; s += w * w; }
    nsq1[gid] = 1.0f + s;      // +1 keeps d positive -> u32-monotone float bits
    used[gid] = 0;
  }
  if (gid == 0) { *done = 0; *usedCnt = 0; *lossAcc = 0.f; }
}

// ---- M: block = 128 px; wave = 64 px x 512 codes (half-split); B via LDS ----
// R3/R9 post-mortem: fused finalize with RELEASE done-counter cost +26us
// (vq_main 41.5 -> 67.5us, all pipes idle). Mechanism: agent-scope RELEASE
// RMW emits buffer_wbl2 + vmcnt(0) -> each of 512 blocks synchronously
// flushes its XCD's dirty L2 (its ~0.5MB out-stream) in-kernel, serializing
// what is normally lazy post-kernel writeback. R10: NO fences anywhere.
// All cross-block state is returning agent-scope RMWs (IC-performed at
// vmcnt-retire — data path proven bit-correct in R3's passing run); t0
// orders lossAcc-add before done-add with a single-lane s_waitcnt vmcnt(0)
// (~0.3us, no L2 flush). atomicOr result consumed AFTER the gather loop so
// its IC latency hides under 256KB of gather traffic.
// Math (verified R4-R6): A=bf16(-2z), MFMA C-init = 1+||e||^2 -> d directly;
// key=(bits(d)&~1023)|code, argmin via u32 min.
__global__ __launch_bounds__(256, 3)
void vq_main(const float* __restrict__ zin,
             const unsigned short* __restrict__ ebf,
             const float* __restrict__ nsq1,
             int* __restrict__ used,
             unsigned int* __restrict__ done,
             int* __restrict__ usedCnt,
             float* __restrict__ lossAcc,
             float* __restrict__ out) {
  __shared__ __align__(16) uint4 bG[2][1024];   // 2 x 16KB: 64-code chunks
  __shared__ float nsq_s[K_CODES];
  __shared__ unsigned int mergeK[128][2];
  __shared__ int   widx[128];
  __shared__ float wsum[4];

  const int t  = threadIdx.x;
  const int L  = t & 63;
  const int wv = t >> 6;        // wave 0..3
  const int ph = wv >> 1;       // pixel half: px [ph*64, ph*64+64)
  const int kh = wv & 1;        // code half: jj tiles {kh*2, kh*2+1}
  const int q  = L >> 4;        // lane quad
  const int nL = L & 15;

  const int bb = blockIdx.x >> 5;          // batch 0..15
  const int hg = blockIdx.x & 31;          // 128-px group
  const int zoff = bb * (C_DIM * 4096) + hg * 128;   // + c*4096 + p

  for (int i = t; i < K_CODES; i += 256) nsq_s[i] = nsq1[i];

  // ---- A fragments straight from global, packed bf16(-2z) in-register
  // lane L, m-tile mt (0..3): pixel = ph*64 + mt*16 + nL, k = ks*32 + q*8 + u
  short8 afrag[16];
  #pragma unroll
  for (int mt = 0; mt < 4; ++mt) {
    const int wcol = ph * 64 + mt * 16 + nL;
    #pragma unroll
    for (int ks = 0; ks < 4; ++ks) {
      float v[8];
      #pragma unroll
      for (int u = 0; u < 8; ++u)
        v[u] = zin[zoff + (ks * 32 + q * 8 + u) * 4096 + wcol];
      U16x8 pk;
      pk.u.x = f2bf2(-2.f * v[0], -2.f * v[1]);
      pk.u.y = f2bf2(-2.f * v[2], -2.f * v[3]);
      pk.u.z = f2bf2(-2.f * v[4], -2.f * v[5]);
      pk.u.w = f2bf2(-2.f * v[6], -2.f * v[7]);
      afrag[mt * 4 + ks] = pk.s;
    }
  }

  // ---- staging thread roles (contiguous 1KB per wave-instruction)
  const uint4* __restrict__ ebv = (const uint4*)ebf;   // granule view, row=16
  const int nLw = t >> 4;        // row-within-group 0..15
  const int oct = t & 15;        // granule-within-row
  const int sks = oct >> 2, sq = oct & 3;

  // stage chunk 0
  #pragma unroll
  for (int p = 0; p < 4; ++p) {
    int r = p * 16 + nLw;                        // row within chunk
    bG[0][p * 256 + sks * 64 + nLw * 4 + sq] = ebv[r * 16 + oct];
  }
  __syncthreads();

  unsigned int kmin[16];
  #pragma unroll
  for (int i = 0; i < 16; ++i) kmin[i] = 0xFFFFFFFFu;

  // ---- K loop: 16 chunks; this wave consumes its 2 jj-tiles (32 codes)
  #pragma unroll 1
  for (int ch = 0; ch < 16; ++ch) {
    const int cur = ch & 1;
    if (ch < 15) {                               // stage next chunk into !cur
      #pragma unroll
      for (int p = 0; p < 4; ++p) {
        int r = p * 16 + nLw;
        bG[cur ^ 1][p * 256 + sks * 64 + nLw * 4 + sq] =
            ebv[((ch + 1) * 64 + r) * 16 + oct];
      }
    }
    const short8* bp = (const short8*)bG[cur];
    #pragma unroll
    for (int j2 = 0; j2 < 2; ++j2) {
      const int jj = kh * 2 + j2;
      const int row = ch * 64 + jj * 16 + nL;    // this lane's code
      short8 b0 = bp[jj * 256 + 0 * 64 + nL * 4 + q];
      short8 b1 = bp[jj * 256 + 1 * 64 + nL * 4 + q];
      short8 b2 = bp[jj * 256 + 2 * 64 + nL * 4 + q];
      short8 b3 = bp[jj * 256 + 3 * 64 + nL * 4 + q];
      const float nv = nsq_s[row];
      f32x4 a0 = {nv, nv, nv, nv};
      f32x4 a1 = {nv, nv, nv, nv};
      f32x4 a2 = {nv, nv, nv, nv};
      f32x4 a3 = {nv, nv, nv, nv};
      a0 = __builtin_amdgcn_mfma_f32_16x16x32_bf16(afrag[0],  b0, a0, 0, 0, 0);
      a1 = __builtin_amdgcn_mfma_f32_16x16x32_bf16(afrag[4],  b0, a1, 0, 0, 0);
      a2 = __builtin_amdgcn_mfma_f32_16x16x32_bf16(afrag[8],  b0, a2, 0, 0, 0);
      a3 = __builtin_amdgcn_mfma_f32_16x16x32_bf16(afrag[12], b0, a3, 0, 0, 0);
      a0 = __builtin_amdgcn_mfma_f32_16x16x32_bf16(afrag[1],  b1, a0, 0, 0, 0);
      a1 = __builtin_amdgcn_mfma_f32_16x16x32_bf16(afrag[5],  b1, a1, 0, 0, 0);
      a2 = __builtin_amdgcn_mfma_f32_16x16x32_bf16(afrag[9],  b1, a2, 0, 0, 0);
      a3 = __builtin_amdgcn_mfma_f32_16x16x32_bf16(afrag[13], b1, a3, 0, 0, 0);
      a0 = __builtin_amdgcn_mfma_f32_16x16x32_bf16(afrag[2],  b2, a0, 0, 0, 0);
      a1 = __builtin_amdgcn_mfma_f32_16x16x32_bf16(afrag[6],  b2, a1, 0, 0, 0);
      a2 = __builtin_amdgcn_mfma_f32_16x16x32_bf16(afrag[10], b2, a2, 0, 0, 0);
      a3 = __builtin_amdgcn_mfma_f32_16x16x32_bf16(afrag[14], b2, a3, 0, 0, 0);
      a0 = __builtin_amdgcn_mfma_f32_16x16x32_bf16(afrag[3],  b3, a0, 0, 0, 0);
      a1 = __builtin_amdgcn_mfma_f32_16x16x32_bf16(afrag[7],  b3, a1, 0, 0, 0);
      a2 = __builtin_amdgcn_mfma_f32_16x16x32_bf16(afrag[11], b3, a2, 0, 0, 0);
      a3 = __builtin_amdgcn_mfma_f32_16x16x32_bf16(afrag[15], b3, a3, 0, 0, 0);
      const unsigned int rowc = (unsigned int)row;
      #pragma unroll
      for (int r = 0; r < 4; ++r) {
        unsigned int k0 = (__float_as_uint(a0[r]) & 0xFFFFFC00u) | rowc;
        if (k0 < kmin[r]) kmin[r] = k0;
        unsigned int k1 = (__float_as_uint(a1[r]) & 0xFFFFFC00u) | rowc;
        if (k1 < kmin[4 + r]) kmin[4 + r] = k1;
        unsigned int k2 = (__float_as_uint(a2[r]) & 0xFFFFFC00u) | rowc;
        if (k2 < kmin[8 + r]) kmin[8 + r] = k2;
        unsigned int k3 = (__float_as_uint(a3[r]) & 0xFFFFFC00u) | rowc;
        if (k3 < kmin[12 + r]) kmin[12 + r] = k3;
      }
    }
    __syncthreads();   // next-chunk writes visible; cur free for re-stage
  }

  // ---- in-wave butterfly u32-min over the 16 code-lanes of each quad
  #pragma unroll
  for (int m = 1; m <= 8; m <<= 1) {
    #pragma unroll
    for (int i = 0; i < 16; ++i) {
      unsigned int o = (unsigned int)__shfl_xor((int)kmin[i], m, 64);
      if (o < kmin[i]) kmin[i] = o;
    }
  }
  if (nL == 0) {
    #pragma unroll
    for (int mt = 0; mt < 4; ++mt)
      #pragma unroll
      for (int r = 0; r < 4; ++r)
        mergeK[ph * 64 + mt * 16 + q * 4 + r][kh] = kmin[mt * 4 + r];
  }
  __syncthreads();

  // ---- cross-half merge (2-way u32 min per pixel)
  if (t < 128) {
    unsigned int b = min(mergeK[t][0], mergeK[t][1]);
    widx[t] = (int)(b & 1023u);
  }
  __syncthreads();

  // ---- used-dedup: issue the IC RMW now, consume its result after gather
  int myold = 1;
  if (t < 128) myold = atomicOr(&used[widx[t]], 1);

  // ---- gather bf16 e-row + coalesced z/out + loss partial
  float lsum = 0.f;
  {
    const int p = t & 127, cg = t >> 7;    // 2 channel halves x 64 ch
    const int idx = widx[p];
    const uint4* erow = ebv + idx * 16 + cg * 8;
    const int obase = zoff + cg * 64 * 4096 + p;
    #pragma unroll 2
    for (int i = 0; i < 8; ++i) {
      uint4 g = erow[i];
      const unsigned int wrd[4] = {g.x, g.y, g.z, g.w};
      #pragma unroll
      for (int half = 0; half < 4; ++half) {
        float e0 = __uint_as_float(wrd[half] << 16);
        float e1 = __uint_as_float(wrd[half] & 0xFFFF0000u);
        int off = obase + (i * 8 + half * 2) * 4096;
        float d0 = zin[off] - e0;
        out[off] = e0;                     // lanes over p -> 256B contiguous
        lsum += d0 * d0;
        off += 4096;
        float d1 = zin[off] - e1;
        out[off] = e1;
        lsum += d1 * d1;
      }
    }
  }
  #pragma unroll
  for (int o = 32; o > 0; o >>= 1) lsum += __shfl_down(lsum, o, 64);
  if (L == 0) wsum[wv] = lsum;

  // atomicOr latency was hidden under the gather loop above
  if (t < 128 && myold == 0) {
    int d = atomicAdd(usedCnt, 1);           // returning form (sink keeps it)
    asm volatile("" :: "v"(d));
  }
  __syncthreads();
  // barrier drain: every wave's RMWs retired == performed at IC

  // ---- fused finalize: no fences, no wbl2 — IC-resident RMW state only
  if (t == 0) {
    float bs = wsum[0] + wsum[1] + wsum[2] + wsum[3];
    float oldl = __hip_atomic_fetch_add(lossAcc, bs, __ATOMIC_RELAXED,
                                        __HIP_MEMORY_SCOPE_AGENT);
    // single-lane vmcnt(0): lossAcc add performed at IC before done bump
    asm volatile("s_waitcnt vmcnt(0)" :: "v"(oldl) : "memory");
    unsigned int oldc = __hip_atomic_fetch_add(done, 1u, __ATOMIC_RELAXED,
                                               __HIP_MEMORY_SCOPE_AGENT);
    if (oldc == (unsigned int)(NBLK - 1)) {
      // all 511 other blocks' RMWs performed (their vmcnt-retire preceded
      // their done bump); agent-scope atomic loads read IC, bypass stale L2
      float ltot = __hip_atomic_load(lossAcc, __ATOMIC_RELAXED,
                                     __HIP_MEMORY_SCOPE_AGENT);
      int   uc   = __hip_atomic_load(usedCnt, __ATOMIC_RELAXED,
                                     __HIP_MEMORY_SCOPE_AGENT);
      out[TOT]     = 1.25f * ltot / (float)TOT;  // (1+0.25)*MSE
      out[TOT + 1] = (float)uc / 1024.0f;
    }
  }
}

extern "C" void kernel_launch(void* const* d_in, const int* in_sizes, int n_in,
                              void* d_out, int out_size, void* d_ws, size_t ws_size,
                              hipStream_t stream) {
  const float* z  = (const float*)d_in[0];
  const float* cb = (const float*)d_in[1];
  float* out = (float*)d_out;
  char* ws = (char*)d_ws;
  unsigned short* ebf = (unsigned short*)ws;          // 262144 B
  float* nsq1  = (float*)(ws + 262144);               // 4096 B
  int*   used  = (int*)(ws + 266240);                 // 4096 B
  unsigned int* done = (unsigned int*)(ws + 270336);  // 4 B
  int*   usedCnt = (int*)(ws + 270352);               // 4 B
  float* lossAcc = (float*)(ws + 270368);             // 4 B

  hipLaunchKernelGGL(prep_kernel, dim3(128), dim3(256), 0, stream,
                     cb, ebf, nsq1, used, done, usedCnt, lossAcc);
  hipLaunchKernelGGL(vq_main, dim3(NBLK), dim3(256), 0, stream,
                     z, ebf, nsq1, used, done, usedCnt, lossAcc, out);
}

// Round 5
// 116.904 us; speedup vs baseline: 1.2173x; 1.1202x over previous
//
#include <hip/hip_runtime.h>

typedef __attribute__((ext_vector_type(8))) short short8;
typedef __attribute__((ext_vector_type(4))) float f32x4;

#define C_DIM 128
#define K_CODES 1024
#define TOT 8388608   // 16*128*64*64
#define NBLK 512      // 128 contiguous pixels per block

__device__ __forceinline__ unsigned int f2bf1(float f) {
  unsigned int u = __float_as_uint(f);
  return (u + 0x7FFFu + ((u >> 16) & 1u)) >> 16;   // RNE fp32->bf16
}
__device__ __forceinline__ unsigned int f2bf2(float lo, float hi) {
  return f2bf1(lo) | (f2bf1(hi) << 16);
}

union U16x8 { uint4 u; short8 s; };

// ---- P: bf16 codebook + (1 + ||e||^2) + zero used ----
// Grid 128: 32768 threads x (16B read / 8B write) == K*C exactly (R8 lesson).
__global__ void prep_kernel(const float* __restrict__ cb,
                            unsigned short* __restrict__ ebf,
                            float* __restrict__ nsq1,
                            int* __restrict__ used) {
  int gid = blockIdx.x * 256 + threadIdx.x;     // 128 blocks * 256 = 32768 = K*C/4
  const float4 v = ((const float4*)cb)[gid];    // 32768*16B = 512KB = cb size
  uint2 pk;
  pk.x = f2bf2(v.x, v.y);
  pk.y = f2bf2(v.z, v.w);
  ((uint2*)ebf)[gid] = pk;                      // 32768*8B = 256KB = ebf size
  if (gid < K_CODES) {
    float s = 0.f;
    #pragma unroll 8
    for (int c = 0; c < C_DIM; ++c) { float w = cb[gid * C_DIM + c]; s += w * w; }
    nsq1[gid] = 1.0f + s;      // +1 keeps d positive -> u32-monotone float bits
    used[gid] = 0;
  }
}

// ---- M: block = 128 px; 8 waves x (32 px x 512 codes); B via LDS ----
// R4 post-mortem: epilogue atomics (atomicOr dedup + RMW-ordered finalize)
// cost +17us over plain stores -> REVERTED to R0 epilogue (plain used[]=1,
// lossp store, separate finalize; kernel boundary = free coherence).
// R4 counter read: FETCH+WRITE = 65MB only -> z/out are L3-resident across
// iterations; vq_main is LATENCY-bound at 17% occupancy (2 waves/SIMD),
// not HBM-bound. R11: 512 threads / 8 waves per block -> 4 waves/SIMD.
// Wave = px-quarter (ph=wv>>1) x code-half (kh=wv&1): afrag halves to 8,
// same total MFMA/ds_read, 2x latency hiding on every LDS/L2 stall.
// Math (verified R4-R6): A=bf16(-2z), MFMA C-init = 1+||e||^2 -> d directly;
// key=(bits(d)&~1023)|code, argmin via u32 min.
__global__ __launch_bounds__(512, 4)
void vq_main(const float* __restrict__ zin,
             const unsigned short* __restrict__ ebf,
             const float* __restrict__ nsq1,
             int* __restrict__ used, float* __restrict__ lossp,
             float* __restrict__ out) {
  __shared__ __align__(16) uint4 bG[2][1024];   // 2 x 16KB: 64-code chunks
  __shared__ float nsq_s[K_CODES];
  __shared__ unsigned int mergeK[128][2];
  __shared__ int   widx[128];
  __shared__ float wsum[8];

  const int t  = threadIdx.x;        // 0..511
  const int L  = t & 63;
  const int wv = t >> 6;             // wave 0..7
  const int ph = wv >> 1;            // pixel quarter: px [ph*32, ph*32+32)
  const int kh = wv & 1;             // code half: jj tiles {kh*2, kh*2+1}
  const int q  = L >> 4;             // lane quad
  const int nL = L & 15;

  const int bb = blockIdx.x >> 5;          // batch 0..15
  const int hg = blockIdx.x & 31;          // 128-px group
  const int zoff = bb * (C_DIM * 4096) + hg * 128;   // + c*4096 + p

  for (int i = t; i < K_CODES; i += 512) nsq_s[i] = nsq1[i];

  // ---- A fragments straight from global, packed bf16(-2z) in-register
  // lane L, m-tile mt (0..1): pixel = ph*32 + mt*16 + nL, k = ks*32 + q*8 + u
  short8 afrag[8];
  #pragma unroll
  for (int mt = 0; mt < 2; ++mt) {
    const int wcol = ph * 32 + mt * 16 + nL;
    #pragma unroll
    for (int ks = 0; ks < 4; ++ks) {
      float v[8];
      #pragma unroll
      for (int u = 0; u < 8; ++u)
        v[u] = zin[zoff + (ks * 32 + q * 8 + u) * 4096 + wcol];
      U16x8 pk;
      pk.u.x = f2bf2(-2.f * v[0], -2.f * v[1]);
      pk.u.y = f2bf2(-2.f * v[2], -2.f * v[3]);
      pk.u.z = f2bf2(-2.f * v[4], -2.f * v[5]);
      pk.u.w = f2bf2(-2.f * v[6], -2.f * v[7]);
      afrag[mt * 4 + ks] = pk.s;
    }
  }

  // ---- staging thread roles: 512 threads x 2 granules = 1024 x 16B / chunk
  const uint4* __restrict__ ebv = (const uint4*)ebf;   // granule view, row=16
  const int nLw = (t >> 4) & 15;     // row-within-group
  const int oct = t & 15;            // granule-within-row
  const int pb  = t >> 8;            // 0..1 -> p = pb + 2*i
  const int sks = oct >> 2, sq = oct & 3;

  // stage chunk 0
  #pragma unroll
  for (int i = 0; i < 2; ++i) {
    int p = pb + 2 * i;                          // row-group within chunk
    bG[0][p * 256 + sks * 64 + nLw * 4 + sq] = ebv[(p * 16 + nLw) * 16 + oct];
  }
  __syncthreads();

  unsigned int kmin[8];
  #pragma unroll
  for (int i = 0; i < 8; ++i) kmin[i] = 0xFFFFFFFFu;

  // ---- K loop: 16 chunks; this wave consumes its 2 jj-tiles (32 codes)
  #pragma unroll 1
  for (int ch = 0; ch < 16; ++ch) {
    const int cur = ch & 1;
    if (ch < 15) {                               // stage next chunk into !cur
      #pragma unroll
      for (int i = 0; i < 2; ++i) {
        int p = pb + 2 * i;
        bG[cur ^ 1][p * 256 + sks * 64 + nLw * 4 + sq] =
            ebv[((ch + 1) * 64 + p * 16 + nLw) * 16 + oct];
      }
    }
    const short8* bp = (const short8*)bG[cur];
    #pragma unroll
    for (int j2 = 0; j2 < 2; ++j2) {
      const int jj = kh * 2 + j2;
      const int row = ch * 64 + jj * 16 + nL;    // this lane's code
      short8 b0 = bp[jj * 256 + 0 * 64 + nL * 4 + q];
      short8 b1 = bp[jj * 256 + 1 * 64 + nL * 4 + q];
      short8 b2 = bp[jj * 256 + 2 * 64 + nL * 4 + q];
      short8 b3 = bp[jj * 256 + 3 * 64 + nL * 4 + q];
      const float nv = nsq_s[row];
      f32x4 c0 = {nv, nv, nv, nv};
      f32x4 c1 = {nv, nv, nv, nv};
      c0 = __builtin_amdgcn_mfma_f32_16x16x32_bf16(afrag[0], b0, c0, 0, 0, 0);
      c1 = __builtin_amdgcn_mfma_f32_16x16x32_bf16(afrag[4], b0, c1, 0, 0, 0);
      c0 = __builtin_amdgcn_mfma_f32_16x16x32_bf16(afrag[1], b1, c0, 0, 0, 0);
      c1 = __builtin_amdgcn_mfma_f32_16x16x32_bf16(afrag[5], b1, c1, 0, 0, 0);
      c0 = __builtin_amdgcn_mfma_f32_16x16x32_bf16(afrag[2], b2, c0, 0, 0, 0);
      c1 = __builtin_amdgcn_mfma_f32_16x16x32_bf16(afrag[6], b2, c1, 0, 0, 0);
      c0 = __builtin_amdgcn_mfma_f32_16x16x32_bf16(afrag[3], b3, c0, 0, 0, 0);
      c1 = __builtin_amdgcn_mfma_f32_16x16x32_bf16(afrag[7], b3, c1, 0, 0, 0);
      const unsigned int rowc = (unsigned int)row;
      #pragma unroll
      for (int r = 0; r < 4; ++r) {
        unsigned int k0 = (__float_as_uint(c0[r]) & 0xFFFFFC00u) | rowc;
        if (k0 < kmin[r]) kmin[r] = k0;
        unsigned int k1 = (__float_as_uint(c1[r]) & 0xFFFFFC00u) | rowc;
        if (k1 < kmin[4 + r]) kmin[4 + r] = k1;
      }
    }
    __syncthreads();   // next-chunk writes visible; cur free for re-stage
  }

  // ---- in-wave butterfly u32-min over the 16 code-lanes of each quad
  #pragma unroll
  for (int m = 1; m <= 8; m <<= 1) {
    #pragma unroll
    for (int i = 0; i < 8; ++i) {
      unsigned int o = (unsigned int)__shfl_xor((int)kmin[i], m, 64);
      if (o < kmin[i]) kmin[i] = o;
    }
  }
  if (nL == 0) {
    #pragma unroll
    for (int mt = 0; mt < 2; ++mt)
      #pragma unroll
      for (int r = 0; r < 4; ++r)
        mergeK[ph * 32 + mt * 16 + q * 4 + r][kh] = kmin[mt * 4 + r];
  }
  __syncthreads();

  // ---- cross-half merge (2-way u32 min per pixel); plain used store (R0)
  if (t < 128) {
    unsigned int b = min(mergeK[t][0], mergeK[t][1]);
    int bi = (int)(b & 1023u);
    widx[t] = bi;
    used[bi] = 1;   // benign same-value race; kernel boundary = coherence
  }
  __syncthreads();

  // ---- gather bf16 e-row + coalesced z/out + loss partial
  float lsum = 0.f;
  {
    const int p = t & 127, cg = t >> 7;    // 4 channel groups x 32 ch
    const int idx = widx[p];
    const uint4* erow = ebv + idx * 16 + cg * 4;
    const int obase = zoff + cg * 32 * 4096 + p;
    #pragma unroll
    for (int i = 0; i < 4; ++i) {
      uint4 g = erow[i];
      const unsigned int wrd[4] = {g.x, g.y, g.z, g.w};
      #pragma unroll
      for (int half = 0; half < 4; ++half) {
        float e0 = __uint_as_float(wrd[half] << 16);
        float e1 = __uint_as_float(wrd[half] & 0xFFFF0000u);
        int off = obase + (i * 8 + half * 2) * 4096;
        float d0 = zin[off] - e0;
        out[off] = e0;                     // lanes over p -> 256B contiguous
        lsum += d0 * d0;
        off += 4096;
        float d1 = zin[off] - e1;
        out[off] = e1;
        lsum += d1 * d1;
      }
    }
  }
  #pragma unroll
  for (int o = 32; o > 0; o >>= 1) lsum += __shfl_down(lsum, o, 64);
  if (L == 0) wsum[wv] = lsum;
  __syncthreads();
  if (t == 0)
    lossp[blockIdx.x] = ((wsum[0] + wsum[1]) + (wsum[2] + wsum[3]))
                      + ((wsum[4] + wsum[5]) + (wsum[6] + wsum[7]));
}

// ---- F: usage count + loss finalize ----
__global__ void finalize_kernel(const int* __restrict__ used,
                                const float* __restrict__ lossp,
                                float* __restrict__ out2) {
  __shared__ int   redi[256];
  __shared__ float redf[256];
  int t = threadIdx.x;
  int s = 0;
  for (int i = t; i < K_CODES; i += 256) s += (used[i] != 0) ? 1 : 0;
  float ls = 0.f;
  for (int i = t; i < NBLK; i += 256) ls += lossp[i];
  redi[t] = s; redf[t] = ls;
  __syncthreads();
  for (int o = 128; o > 0; o >>= 1) {
    if (t < o) { redi[t] += redi[t + o]; redf[t] += redf[t + o]; }
    __syncthreads();
  }
  if (t == 0) {
    out2[0] = 1.25f * redf[0] / (float)TOT;  // (1+0.25)*MSE
    out2[1] = (float)redi[0] / 1024.0f;
  }
}

extern "C" void kernel_launch(void* const* d_in, const int* in_sizes, int n_in,
                              void* d_out, int out_size, void* d_ws, size_t ws_size,
                              hipStream_t stream) {
  const float* z  = (const float*)d_in[0];
  const float* cb = (const float*)d_in[1];
  float* out = (float*)d_out;
  char* ws = (char*)d_ws;
  unsigned short* ebf = (unsigned short*)ws;          // 262144 B
  float* nsq1  = (float*)(ws + 262144);               // 4096 B
  int*   used  = (int*)(ws + 266240);                 // 4096 B
  float* lossp = (float*)(ws + 270336);               // 2048 B (per-block partials)

  hipLaunchKernelGGL(prep_kernel, dim3(128), dim3(256), 0, stream,
                     cb, ebf, nsq1, used);
  hipLaunchKernelGGL(vq_main, dim3(NBLK), dim3(512), 0, stream,
                     z, ebf, nsq1, used, lossp, out);
  hipLaunchKernelGGL(finalize_kernel, dim3(1), dim3(256), 0, stream,
                     used, lossp, out + TOT);
}